// Round 15
// baseline (344.521 us; speedup 1.0000x reference)
//
#include <hip/hip_runtime.h>
#include <cstdio>

// Problem constants
constexpr int B_   = 2;
constexpr int S_   = 2048;
constexpr int D_   = 1024;
constexpr int H_   = 16;
constexpr int DFF_ = 4096;
constexpr int DK_  = D_ / H_;   // 64
constexpr int M_   = B_ * S_;   // 4096 tokens
constexpr float EPS_ = 1e-5f;
constexpr size_t MEGE = 1u << 20;          // 1M elems
constexpr size_t QKV_STRIDE = 4 * MEGE;    // Q->K->V slot stride (elems)
constexpr float QSCALE_ = 0.18033688011112042f;  // 0.125 * log2(e): folded into Q

typedef __attribute__((ext_vector_type(8))) short bf16x8;
typedef __attribute__((ext_vector_type(4))) float f32x4;

// ---------- bf16 helpers ----------
__device__ __forceinline__ float bf2f(unsigned int u) {
    return __uint_as_float(u << 16);
}
__device__ __forceinline__ unsigned short f2bf(float f) {          // RTNE
    unsigned int u = __float_as_uint(f);
    unsigned int r = u + 0x7fffu + ((u >> 16) & 1u);
    return (unsigned short)(r >> 16);
}
__device__ __forceinline__ unsigned short f2bf_rz(float f) {       // truncate (P matrix only)
    return (unsigned short)(__float_as_uint(f) >> 16);
}
// 2^x via native v_exp_f32 (NOT __exp2f — glibc macro collision; v_exp_f32 IS exp2).
__device__ __forceinline__ float exp2_fast(float x) {
    float r;
    asm("v_exp_f32 %0, %1" : "=v"(r) : "v"(x));
    return r;
}

// ---------- async global->LDS, 16B per lane ----------
__device__ __forceinline__ void gload_lds16(const unsigned short* g, unsigned short* l) {
    __builtin_amdgcn_global_load_lds(
        (const __attribute__((address_space(1))) unsigned int*)g,
        (__attribute__((address_space(3))) unsigned int*)l, 16, 0, 0);
}

// ---------- fused preprocessing: 6 weight transposes + x convert, ONE launch ----
__device__ __forceinline__ void tr32(const float* __restrict__ W, unsigned short* __restrict__ Wt,
                                     int K, int N, int bx, int by, float* t /*[32*33]*/)
{
    const int tx = threadIdx.x & 31, ty = threadIdx.x >> 5;   // 32 x 8
    const int n0 = bx * 32, k0 = by * 32;
    #pragma unroll
    for (int p = 0; p < 4; ++p)
        t[(ty + p * 8) * 33 + tx] = W[(size_t)(k0 + ty + p * 8) * N + n0 + tx];
    __syncthreads();
    #pragma unroll
    for (int p = 0; p < 4; ++p)
        Wt[(size_t)(n0 + ty + p * 8) * K + k0 + tx] = f2bf(t[tx * 33 + ty + p * 8]);
}

__global__ __launch_bounds__(256)
void prep_k(const float* __restrict__ wq, const float* __restrict__ wk,
            const float* __restrict__ wv, const float* __restrict__ wo,
            const float* __restrict__ w1, const float* __restrict__ w2,
            const float* __restrict__ x,
            unsigned short* __restrict__ wqt, unsigned short* __restrict__ wkt,
            unsigned short* __restrict__ wvt, unsigned short* __restrict__ wot,
            unsigned short* __restrict__ w1t, unsigned short* __restrict__ w2t,
            unsigned short* __restrict__ xb)
{
    __shared__ float t[32 * 33];
    const int bid = blockIdx.x;
    if (bid < 4096) {
        const int z = bid >> 10, rem = bid & 1023;
        const float* W = (z == 0) ? wq : (z == 1) ? wk : (z == 2) ? wv : wo;
        unsigned short* Wt = (z == 0) ? wqt : (z == 1) ? wkt : (z == 2) ? wvt : wot;
        tr32(W, Wt, D_, D_, rem & 31, rem >> 5, t);
    } else if (bid < 8192) {
        const int rem = bid - 4096;
        tr32(w1, w1t, D_, DFF_, rem & 127, rem >> 7, t);
    } else if (bid < 12288) {
        const int rem = bid - 8192;
        tr32(w2, w2t, DFF_, D_, rem & 31, rem >> 5, t);
    } else {
        const int i = (bid - 12288) * 256 + threadIdx.x;
        float4 f = reinterpret_cast<const float4*>(x)[i];
        ushort4 u;
        u.x = f2bf(f.x); u.y = f2bf(f.y); u.z = f2bf(f.z); u.w = f2bf(f.w);
        reinterpret_cast<ushort4*>(xb)[i] = u;
    }
}

// ---------- mg3: 16-wave 256x256 MFMA GEMM (QKV / FFN-up) ----------
template<int OMODE, bool RELU>
__global__ __launch_bounds__(1024, 1)
void mg3_k(const unsigned short* __restrict__ A,
           const unsigned short* __restrict__ Bt,
           const float* __restrict__ bias,
           unsigned short* __restrict__ C,
           int M, int N, int K, int Kld)
{
    __shared__ __align__(16) unsigned short As[2][256 * 64];
    __shared__ __align__(16) unsigned short Bs[2][256 * 64];

    const int tid = threadIdx.x;
    const int w = tid >> 6, lane = tid & 63;
    const int l15 = lane & 15, quad = lane >> 4;
    const int wm = w >> 2, wn = w & 3;              // 4M x 4N wave grid
    const int m0 = blockIdx.y * 256, n0 = blockIdx.x * 256;
    const int NT = K >> 6;

    const int srow = lane >> 3;                     // DMA row within 8-row group
    const int schk = (lane & 7) ^ srow;             // pre-swizzled source chunk
    const int rsw  = l15 & 7;                       // read-side swizzle key

    f32x4 acc[4][4];
    #pragma unroll
    for (int i = 0; i < 4; ++i)
        #pragma unroll
        for (int j = 0; j < 4; ++j) acc[i][j] = (f32x4){0.f, 0.f, 0.f, 0.f};

    auto stageAB = [&](int tile) {
        if (tile >= NT) return;
        const int buf = tile & 1;
        const int k0 = tile * 64;
        #pragma unroll
        for (int g = 0; g < 2; ++g) {
            const int r = w * 16 + g * 8;
            gload_lds16(A + (size_t)(m0 + r + srow) * Kld + k0 + schk * 8, &As[buf][r * 64]);
        }
        #pragma unroll
        for (int g = 0; g < 2; ++g) {
            const int r = w * 16 + g * 8;
            gload_lds16(Bt + (size_t)(n0 + r + srow) * Kld + k0 + schk * 8, &Bs[buf][r * 64]);
        }
    };

    bf16x8 a[4], b[4];
    auto rd = [&](int buf, int h) {
        #pragma unroll
        for (int i = 0; i < 4; ++i) {
            const unsigned short* rp = &As[buf][(wm * 64 + i * 16 + l15) * 64];
            a[i] = *reinterpret_cast<const bf16x8*>(rp + (((quad + 4 * h) ^ rsw) << 3));
        }
        #pragma unroll
        for (int j = 0; j < 4; ++j) {
            const unsigned short* rp = &Bs[buf][(wn * 64 + j * 16 + l15) * 64];
            b[j] = *reinterpret_cast<const bf16x8*>(rp + (((quad + 4 * h) ^ rsw) << 3));
        }
    };
    auto mm16 = [&]() {
        __builtin_amdgcn_s_setprio(1);
        #pragma unroll
        for (int i = 0; i < 4; ++i)
            #pragma unroll
            for (int j = 0; j < 4; ++j)
                acc[i][j] = __builtin_amdgcn_mfma_f32_16x16x32_bf16(a[i], b[j], acc[i][j], 0, 0, 0);
        __builtin_amdgcn_s_setprio(0);
    };

    stageAB(0);

    for (int t = 0; t < NT; ++t) {
        const int cur = t & 1;
        asm volatile("s_waitcnt vmcnt(0)" ::: "memory");  // drains tile t (issued 1 tile ago)
        __builtin_amdgcn_s_barrier();
        stageAB(t + 1);
        rd(cur, 0);
        __builtin_amdgcn_s_barrier();
        asm volatile("s_waitcnt lgkmcnt(0)" ::: "memory");
        mm16();
        rd(cur, 1);
        __builtin_amdgcn_s_barrier();
        asm volatile("s_waitcnt lgkmcnt(0)" ::: "memory");
        mm16();
    }

    #pragma unroll
    for (int i = 0; i < 4; ++i)
        #pragma unroll
        for (int r = 0; r < 4; ++r) {
            const int m = m0 + wm * 64 + i * 16 + quad * 4 + r;
            #pragma unroll
            for (int j = 0; j < 4; ++j) {
                const int n = n0 + wn * 64 + j * 16 + l15;
                float v = acc[i][j][r];
                if (bias) v += bias[n];
                if (RELU) v = fmaxf(v, 0.0f);
                size_t o;
                if (OMODE == 2) {
                    int mat = n >> 10, nn = n & 1023;
                    int bb = m >> 11, s = m & 2047;
                    int h = nn >> 6, dk = nn & 63;
                    if (mat == 0) v *= QSCALE_;   // fold softmax scale+log2e into Q
                    o = (size_t)mat * QKV_STRIDE + (((size_t)bb * H_ + h) * S_ + s) * DK_ + dk;
                } else {
                    o = (size_t)m * N + n;
                }
                C[o] = f2bf(v);
            }
        }
}

// ---------- mg4: 16-wave 128x256 split-K MFMA GEMM (Wo / FFN-down) ----------
// Same verified mg3 schedule (2 phases/tile, vmcnt(0)+3 barriers, stage(t+1)
// at p0), re-parameterized: BM=128, BN=256, per-wave 32x64 (acc 2x4), LDS
// 96KB -> 1 block/CU, 16 waves. Split-K via blockIdx.z (partials layout as mg2).
// Staging per tile: A = 16 slabs (1/wave), B = 32 slabs (2/wave); 3 gloads/wave.
template<bool RELU>
__global__ __launch_bounds__(1024, 1)
void mg4_k(const unsigned short* __restrict__ A,
           const unsigned short* __restrict__ Bt,
           const float* __restrict__ bias,
           unsigned short* __restrict__ C,
           int M, int N, int K, int Kld)
{
    __shared__ __align__(16) unsigned short As[2][128 * 64];
    __shared__ __align__(16) unsigned short Bs[2][256 * 64];

    const int z = blockIdx.z;
    A  += (size_t)z * K;
    Bt += (size_t)z * K;
    C  += (size_t)z * ((size_t)M * N);

    const int tid = threadIdx.x;
    const int w = tid >> 6, lane = tid & 63;
    const int l15 = lane & 15, quad = lane >> 4;
    const int wm = w >> 2, wn = w & 3;              // 4M x 4N wave grid
    const int m0 = blockIdx.y * 128, n0 = blockIdx.x * 256;
    const int NT = K >> 6;

    const int srow = lane >> 3;
    const int schk = (lane & 7) ^ srow;
    const int rsw  = l15 & 7;

    f32x4 acc[2][4];
    #pragma unroll
    for (int i = 0; i < 2; ++i)
        #pragma unroll
        for (int j = 0; j < 4; ++j) acc[i][j] = (f32x4){0.f, 0.f, 0.f, 0.f};

    auto stageAB = [&](int tile) {
        if (tile >= NT) return;
        const int buf = tile & 1;
        const int k0 = tile * 64;
        // A: 128 rows = 16 slabs of 8; wave w stages slab w
        gload_lds16(A + (size_t)(m0 + w * 8 + srow) * Kld + k0 + schk * 8,
                    &As[buf][w * 8 * 64]);
        // B: 256 rows = 32 slabs of 8; wave w stages slabs 2w, 2w+1
        #pragma unroll
        for (int g = 0; g < 2; ++g) {
            const int r = w * 16 + g * 8;
            gload_lds16(Bt + (size_t)(n0 + r + srow) * Kld + k0 + schk * 8,
                        &Bs[buf][r * 64]);
        }
    };

    bf16x8 a[2], b[4];
    auto rd = [&](int buf, int h) {
        #pragma unroll
        for (int i = 0; i < 2; ++i) {
            const unsigned short* rp = &As[buf][(wm * 32 + i * 16 + l15) * 64];
            a[i] = *reinterpret_cast<const bf16x8*>(rp + (((quad + 4 * h) ^ rsw) << 3));
        }
        #pragma unroll
        for (int j = 0; j < 4; ++j) {
            const unsigned short* rp = &Bs[buf][(wn * 64 + j * 16 + l15) * 64];
            b[j] = *reinterpret_cast<const bf16x8*>(rp + (((quad + 4 * h) ^ rsw) << 3));
        }
    };
    auto mm8 = [&]() {
        __builtin_amdgcn_s_setprio(1);
        #pragma unroll
        for (int i = 0; i < 2; ++i)
            #pragma unroll
            for (int j = 0; j < 4; ++j)
                acc[i][j] = __builtin_amdgcn_mfma_f32_16x16x32_bf16(a[i], b[j], acc[i][j], 0, 0, 0);
        __builtin_amdgcn_s_setprio(0);
    };

    stageAB(0);

    for (int t = 0; t < NT; ++t) {
        const int cur = t & 1;
        asm volatile("s_waitcnt vmcnt(0)" ::: "memory");
        __builtin_amdgcn_s_barrier();
        stageAB(t + 1);
        rd(cur, 0);
        __builtin_amdgcn_s_barrier();
        asm volatile("s_waitcnt lgkmcnt(0)" ::: "memory");
        mm8();
        rd(cur, 1);
        __builtin_amdgcn_s_barrier();
        asm volatile("s_waitcnt lgkmcnt(0)" ::: "memory");
        mm8();
    }

    #pragma unroll
    for (int i = 0; i < 2; ++i)
        #pragma unroll
        for (int r = 0; r < 4; ++r) {
            const int m = m0 + wm * 32 + i * 16 + quad * 4 + r;
            #pragma unroll
            for (int j = 0; j < 4; ++j) {
                const int n = n0 + wn * 64 + j * 16 + l15;
                float v = acc[i][j][r];
                if (bias) v += bias[n];
                if (RELU) v = fmaxf(v, 0.0f);
                C[(size_t)m * N + n] = f2bf(v);
            }
        }
}

// ---------- wave reduction ----------
__device__ __forceinline__ float wave_sum(float v) {
    #pragma unroll
    for (int off = 32; off > 0; off >>= 1) v += __shfl_down(v, off, 64);
    return v;
}

// ---------- flash attention v5 (R8-verified, 56us): 8 waves x 16 q ----------
constexpr int TQ_ = 128;
constexpr int TK_ = 64;
constexpr int NT_ = S_ / TK_;  // 32 kv tiles

__global__ __launch_bounds__(512)
void fattn_k(const unsigned short* __restrict__ Qm, const unsigned short* __restrict__ Km,
             const unsigned short* __restrict__ Vm, unsigned short* __restrict__ O)
{
    const int bh  = blockIdx.x >> 4;     // 16 q-tiles per (b,h)
    const int qt  = blockIdx.x & 15;
    const int tid = threadIdx.x;
    const int w = tid >> 6, lane = tid & 63;
    const int quad = lane >> 4, l15 = lane & 15;
    const int sw = l15 & 7;                          // read-side swizzle key

    __shared__ __align__(16) unsigned short Ks[2][TK_][64];   // K tile [kpos][d]
    __shared__ __align__(16) unsigned short Vt[2][80][64];    // V^T [d][col'] + ones rows 64..79
    __shared__ __align__(16) unsigned short Ps[8][16][64];    // per-wave P [q][col']

    // Q frags: wave w owns q rows qt*128 + w*16 + [0,16)
    bf16x8 qf0, qf1;
    {
        const unsigned short* qp = Qm + ((size_t)bh * S_ + qt * TQ_ + w * 16 + l15) * DK_;
        qf0 = *reinterpret_cast<const bf16x8*>(qp + quad * 8);
        qf1 = *reinterpret_cast<const bf16x8*>(qp + 32 + quad * 8);
    }

    f32x4 o[4];
    f32x4 o4;
    #pragma unroll
    for (int n = 0; n < 4; ++n) o[n] = (f32x4){0.f, 0.f, 0.f, 0.f};
    o4 = (f32x4){0.f, 0.f, 0.f, 0.f};

    const unsigned short* kg0 = Km + (size_t)bh * S_ * DK_;
    const unsigned short* vg0 = Vm + (size_t)bh * S_ * DK_;
    const int dgrp = tid >> 4;     // (waves 0-3 only) 0..15: d-group of 4 dims
    const int vkp  = tid & 15;     // k-position low bits
    const int srow = lane >> 3;               // DMA: lane -> row within 8-row group
    const int schk = (lane & 7) ^ srow;       // pre-swizzled source chunk

    auto stageK = [&](int t, int buf) {
        const unsigned short* src = kg0 + (size_t)t * TK_ * DK_;
        const int wk = w - 4;
        #pragma unroll
        for (int g = 0; g < 2; ++g) {
            const int r0 = wk * 16 + g * 8;
            gload_lds16(src + (size_t)(r0 + srow) * DK_ + schk * 8, &Ks[buf][r0][0]);
        }
    };
    auto loadV = [&](int t, ushort4 (&vp)[4]) {
        const unsigned short* vg = vg0 + (size_t)t * TK_ * DK_;
        #pragma unroll
        for (int p = 0; p < 4; ++p)
            vp[p] = reinterpret_cast<const ushort4*>(vg + (size_t)(vkp + p * 16) * DK_)[dgrp];
    };
    auto storeVt = [&](int buf, ushort4 (&vp)[4]) {
        char* base = reinterpret_cast<char*>(&Vt[buf][dgrp * 4][0]);
        const int cs = vkp >> 1, ch = (vkp & 1) << 3;
        ushort4 pk;
        pk.x = vp[0].x; pk.y = vp[1].x; pk.z = vp[2].x; pk.w = vp[3].x;
        *reinterpret_cast<ushort4*>(base + 0 * 128 + (((cs ^ ((dgrp * 4 + 0) & 7)) << 4) + ch)) = pk;
        pk.x = vp[0].y; pk.y = vp[1].y; pk.z = vp[2].y; pk.w = vp[3].y;
        *reinterpret_cast<ushort4*>(base + 1 * 128 + (((cs ^ ((dgrp * 4 + 1) & 7)) << 4) + ch)) = pk;
        pk.x = vp[0].z; pk.y = vp[1].z; pk.z = vp[2].z; pk.w = vp[3].z;
        *reinterpret_cast<ushort4*>(base + 2 * 128 + (((cs ^ ((dgrp * 4 + 2) & 7)) << 4) + ch)) = pk;
        pk.x = vp[0].w; pk.y = vp[1].w; pk.z = vp[2].w; pk.w = vp[3].w;
        *reinterpret_cast<ushort4*>(base + 3 * 128 + (((cs ^ ((dgrp * 4 + 3) & 7)) << 4) + ch)) = pk;
    };

    // prologue: tile 0 staged; ones rows (denominator trick) init once
    if (w >= 4) stageK(0, 0);
    else {
        ushort4 vp0[4];
        loadV(0, vp0);
        storeVt(0, vp0);
    }
    for (int idx = tid; idx < 2 * 16 * 64; idx += 512) {
        const int b  = idx >> 10;
        const int rr = (idx >> 6) & 15;
        const int cc = idx & 63;
        Vt[b][64 + rr][((cc >> 3) ^ (rr & 7)) * 8 + (cc & 7)] =
            (rr == 0) ? (unsigned short)0x3F80 : (unsigned short)0;
    }

    for (int t = 0; t < NT_; ++t) {
        const int cur = t & 1, nxt = cur ^ 1;
        __syncthreads();   // per-wave vmcnt/lgkm drain + CU-wide LDS ordering

        const bool hn = (t + 1 < NT_);
        ushort4 vp[4];
        if (hn) { if (w >= 4) stageK(t + 1, nxt); else loadV(t + 1, vp); }

        // QK^T: 8 MFMA
        f32x4 s[4];
        __builtin_amdgcn_s_setprio(1);
        #pragma unroll
        for (int n = 0; n < 4; ++n) {
            const unsigned short* kp = &Ks[cur][n * 16 + l15][0];
            bf16x8 b0 = *reinterpret_cast<const bf16x8*>(kp + ((quad ^ sw) << 3));
            bf16x8 b1 = *reinterpret_cast<const bf16x8*>(kp + (((quad + 4) ^ sw) << 3));
            f32x4 a2 = (f32x4){0.f, 0.f, 0.f, 0.f};
            a2 = __builtin_amdgcn_mfma_f32_16x16x32_bf16(qf0, b0, a2, 0, 0, 0);
            a2 = __builtin_amdgcn_mfma_f32_16x16x32_bf16(qf1, b1, a2, 0, 0, 0);
            s[n] = a2;
        }
        __builtin_amdgcn_s_setprio(0);

        // softmax: P = exp2(s) (Q pre-scaled), write per-wave P tile
        #pragma unroll
        for (int r = 0; r < 4; ++r) {
            ushort4 pk;
            pk.x = f2bf_rz(exp2_fast(s[0][r]));
            pk.y = f2bf_rz(exp2_fast(s[1][r]));
            pk.z = f2bf_rz(exp2_fast(s[2][r]));
            pk.w = f2bf_rz(exp2_fast(s[3][r]));
            const int R = quad * 4 + r;
            *reinterpret_cast<ushort4*>(
                reinterpret_cast<char*>(&Ps[w][R][0]) +
                ((((l15 >> 1) ^ (R & 7)) << 4) + ((l15 & 1) << 3))) = pk;
        }

        if (hn && w < 4) storeVt(nxt, vp);

        // PV: 10 MFMA
        bf16x8 pa0, pa1;
        {
            const unsigned short* pp = &Ps[w][l15][0];
            pa0 = *reinterpret_cast<const bf16x8*>(pp + ((quad ^ sw) << 3));
            pa1 = *reinterpret_cast<const bf16x8*>(pp + (((quad + 4) ^ sw) << 3));
        }
        __builtin_amdgcn_s_setprio(1);
        #pragma unroll
        for (int n = 0; n < 4; ++n) {
            const unsigned short* vb = &Vt[cur][n * 16 + l15][0];
            bf16x8 vb0 = *reinterpret_cast<const bf16x8*>(vb + ((quad ^ sw) << 3));
            bf16x8 vb1 = *reinterpret_cast<const bf16x8*>(vb + (((quad + 4) ^ sw) << 3));
            o[n] = __builtin_amdgcn_mfma_f32_16x16x32_bf16(pa0, vb0, o[n], 0, 0, 0);
            o[n] = __builtin_amdgcn_mfma_f32_16x16x32_bf16(pa1, vb1, o[n], 0, 0, 0);
        }
        {
            const unsigned short* vb = &Vt[cur][64 + l15][0];
            bf16x8 vb40 = *reinterpret_cast<const bf16x8*>(vb + ((quad ^ sw) << 3));
            bf16x8 vb41 = *reinterpret_cast<const bf16x8*>(vb + (((quad + 4) ^ sw) << 3));
            o4 = __builtin_amdgcn_mfma_f32_16x16x32_bf16(pa0, vb40, o4, 0, 0, 0);
            o4 = __builtin_amdgcn_mfma_f32_16x16x32_bf16(pa1, vb41, o4, 0, 0, 0);
        }
        __builtin_amdgcn_s_setprio(0);
    }

    const int b = bh >> 4, h = bh & 15;
    #pragma unroll
    for (int r = 0; r < 4; ++r) {
        float lrv = __shfl(o4[r], lane & 0x30, 64);
        float inv = 1.0f / lrv;
        int q = qt * TQ_ + w * 16 + quad * 4 + r;
        unsigned short* op = O + ((size_t)b * S_ + q) * D_ + h * DK_;
        #pragma unroll
        for (int n = 0; n < 4; ++n)
            op[n * 16 + l15] = f2bf(o[n][r] * inv);
    }
}

// ---------- reducing LayerNorm: v = P0+P1 (+bias) (+res), then LN (ddof=1) ----------
template<bool HAS_BIAS, bool RES_F32, bool OUT_F32>
__global__ __launch_bounds__(256)
void lnr_k(const unsigned short* __restrict__ P0, const unsigned short* __restrict__ P1,
           const void* __restrict__ res, const float* __restrict__ bias,
           const float* __restrict__ gp, const float* __restrict__ bp,
           void* __restrict__ Out)
{
    const int row = blockIdx.x;
    const int tid = threadIdx.x;
    const int lane = tid & 63, wave = tid >> 6;
    __shared__ float rs[4], rss[4];

    const size_t i4 = (size_t)row * 256 + tid;
    const ushort4 a = reinterpret_cast<const ushort4*>(P0)[i4];
    const ushort4 b = reinterpret_cast<const ushort4*>(P1)[i4];
    float v0 = bf2f(a.x) + bf2f(b.x);
    float v1 = bf2f(a.y) + bf2f(b.y);
    float v2 = bf2f(a.z) + bf2f(b.z);
    float v3 = bf2f(a.w) + bf2f(b.w);
    if (RES_F32) {
        float4 rv = reinterpret_cast<const float4*>(res)[i4];
        v0 += rv.x; v1 += rv.y; v2 += rv.z; v3 += rv.w;
    } else {
        ushort4 rv = reinterpret_cast<const ushort4*>(res)[i4];
        v0 += bf2f(rv.x); v1 += bf2f(rv.y); v2 += bf2f(rv.z); v3 += bf2f(rv.w);
    }
    if (HAS_BIAS) {
        float4 bv = reinterpret_cast<const float4*>(bias)[tid];
        v0 += bv.x; v1 += bv.y; v2 += bv.z; v3 += bv.w;
    }

    float s  = v0 + v1 + v2 + v3;
    float ss = v0*v0 + v1*v1 + v2*v2 + v3*v3;
    s = wave_sum(s);
    ss = wave_sum(ss);
    if (lane == 0) { rs[wave] = s; rss[wave] = ss; }
    __syncthreads();
    const float stot  = rs[0] + rs[1] + rs[2] + rs[3];
    const float sstot = rss[0] + rss[1] + rss[2] + rss[3];
    const float mean = stot / (float)D_;
    const float var  = (sstot - (float)D_ * mean * mean) / (float)(D_ - 1);
    const float scl = gp[0] * rsqrtf(var + EPS_);
    const float be = bp[0];

    float o0 = (v0 - mean) * scl + be;
    float o1 = (v1 - mean) * scl + be;
    float o2 = (v2 - mean) * scl + be;
    float o3 = (v3 - mean) * scl + be;
    if (OUT_F32) {
        reinterpret_cast<float4*>(Out)[i4] = make_float4(o0, o1, o2, o3);
    } else {
        ushort4 o;
        o.x = f2bf(o0); o.y = f2bf(o1); o.z = f2bf(o2); o.w = f2bf(o3);
        reinterpret_cast<ushort4*>(Out)[i4] = o;
    }
}

// ---------- host launch ----------
extern "C" void kernel_launch(void* const* d_in, const int* in_sizes, int n_in,
                              void* d_out, int out_size, void* d_ws, size_t ws_size,
                              hipStream_t stream)
{
    const float* x   = (const float*)d_in[0];
    const float* wq  = (const float*)d_in[2];
    const float* wk  = (const float*)d_in[3];
    const float* wv  = (const float*)d_in[4];
    const float* wo  = (const float*)d_in[5];
    const float* w1  = (const float*)d_in[6];
    const float* b1  = (const float*)d_in[7];
    const float* w2  = (const float*)d_in[8];
    const float* b2  = (const float*)d_in[9];
    const float* g1  = (const float*)d_in[10];
    const float* be1 = (const float*)d_in[11];
    const float* g2  = (const float*)d_in[12];
    const float* be2 = (const float*)d_in[13];

    unsigned short* ws = (unsigned short*)d_ws;
    const size_t need_bytes = 32 * MEGE * 2;           // 64 MB peak
    if (ws_size < need_bytes) {
        fprintf(stderr, "kernel_launch: ws too small (%zu < %zu)\n", ws_size, need_bytes);
    }
    unsigned short* wqt = ws + 0 * MEGE;
    unsigned short* wkt = ws + 1 * MEGE;
    unsigned short* wvt = ws + 2 * MEGE;
    unsigned short* wot = ws + 3 * MEGE;
    unsigned short* w1t = ws + 4 * MEGE;
    unsigned short* w2t = ws + 8 * MEGE;
    unsigned short* xb  = ws + 12 * MEGE;
    unsigned short* Q   = ws + 16 * MEGE;  // Q,K,V contiguous (QKV_STRIDE apart)
    unsigned short* K   = ws + 20 * MEGE;
    unsigned short* V   = ws + 24 * MEGE;
    unsigned short* AO  = ws + 28 * MEGE;
    unsigned short* x1  = xb;              // LN1 output (xb dead after QKV)
    unsigned short* WP  = ws + 16 * MEGE;  // Wo split-K partials [2][M,D] over dead Q,K
    unsigned short* h1  = ws + 16 * MEGE;  // full [4096,4096] (after LN1)
    unsigned short* FP  = ws + 0 * MEGE;   // FFN-down partials [2][M,D] over dead wqt..w1t

    // 0) fused preprocessing: one launch (4 DxD + w1 + w2 transposes + x convert)
    prep_k<<<dim3(16384), 256, 0, stream>>>(wq, wk, wv, wo, w1, w2, x,
                                            wqt, wkt, wvt, wot, w1t, w2t, xb);

    // 1) fused QKV projection (Q pre-scaled): mg3 16-wave, 192 blocks x 1024 thr
    mg3_k<2, false><<<dim3(3 * D_ / 256, M_ / 256), 1024, 0, stream>>>(
        xb, wqt, nullptr, Q, M_, 3 * D_, D_, D_);

    // 2) flash attention v5 (R8-verified): 512 blocks x 512 threads
    fattn_k<<<dim3(B_ * H_ * (S_ / TQ_)), 512, 0, stream>>>(Q, K, V, AO);

    // 3) Wo split-K=2 (mg4 16-wave): 256 blocks x 1024 thr, partials -> WP[2][M,D]
    mg4_k<false><<<dim3(D_ / 256, M_ / 128, 2), 1024, 0, stream>>>(
        AO, wot, nullptr, WP, M_, D_, D_ / 2, D_);

    // 4) LN1 = reduce(WP0+WP1) + x residual -> x1 (bf16)
    lnr_k<false, true, false><<<dim3(M_), 256, 0, stream>>>(
        WP, WP + 4 * MEGE, x, nullptr, g1, be1, x1);

    // 5) FFN-up: mg3 16-wave, 256 blocks x 1024 thr
    mg3_k<0, true><<<dim3(DFF_ / 256, M_ / 256), 1024, 0, stream>>>(
        x1, w1t, b1, h1, M_, DFF_, D_, D_);

    // 6) FFN-down split-K=2 (mg4 16-wave): 256 blocks x 1024 thr, partials -> FP[2][M,D]
    mg4_k<false><<<dim3(D_ / 256, M_ / 128, 2), 1024, 0, stream>>>(
        h1, w2t, nullptr, FP, M_, D_, DFF_ / 2, DFF_);

    // 7) LN2 = reduce(FP0+FP1) + b2 + x1 residual -> fp32 output
    lnr_k<true, false, true><<<dim3(M_), 256, 0, stream>>>(
        FP, FP + 4 * MEGE, x1, b2, g2, be2, d_out);
}